// Round 1
// baseline (1235.919 us; speedup 1.0000x reference)
//
#include <hip/hip_runtime.h>
#include <stdint.h>

#define VOCAB 16384
#define WIDTH 256
#define NB 32
#define NTOK 8224      // 32*257
#define NTOKP 8256     // 129*64
#define VSPLIT 8
#define VPER 2048      // VOCAB/VSPLIT

// ---------- build token matrix tok[NTOK][256] ----------
__global__ __launch_bounds__(256) void k_class(const float* __restrict__ cls, float* __restrict__ tok) {
    int b = blockIdx.x, c = threadIdx.x;
    tok[(b * 257) * 256 + c] = cls[b * 256 + c];
}

// patch_tokens (B, C, 256) -> tok rows b*257+1+p , col c  (transpose via LDS tiles)
__global__ __launch_bounds__(256) void k_patch(const float* __restrict__ patch, float* __restrict__ tok) {
    __shared__ float t[64][65];
    int c0 = blockIdx.x * 64, p0 = blockIdx.y * 64, b = blockIdx.z;
    int tid = threadIdx.x;
    int l = tid & 63, w = tid >> 6;
    const float* src = patch + b * 65536;
#pragma unroll
    for (int i = 0; i < 16; ++i) {
        int row = i * 4 + w;
        t[row][l] = src[(c0 + row) * 256 + p0 + l];
    }
    __syncthreads();
#pragma unroll
    for (int i = 0; i < 16; ++i) {
        int prow = i * 4 + w;
        tok[(b * 257 + 1 + p0 + prow) * 256 + c0 + l] = t[l][prow];
    }
}

// ---------- row L2 norms (one wave per row) ----------
__global__ __launch_bounds__(256) void k_rownorm(const float* __restrict__ src, float* __restrict__ norms) {
    int r = blockIdx.x * 4 + (threadIdx.x >> 6);
    int lane = threadIdx.x & 63;
    float4 v = *(const float4*)&src[r * 256 + lane * 4];
    float s = v.x * v.x + v.y * v.y + v.z * v.z + v.w * v.w;
#pragma unroll
    for (int off = 32; off > 0; off >>= 1) s += __shfl_down(s, off);
    if (lane == 0) norms[r] = fmaxf(sqrtf(s), 1e-12f);
}

// ---------- transpose + normalize: dst[k][row] = src[row][k] / norms[row] ----------
__global__ __launch_bounds__(256) void k_transpose_scale(const float* __restrict__ src,
                                                         const float* __restrict__ norms,
                                                         float* __restrict__ dst,
                                                         int dstride, int rlimit) {
    __shared__ float t[64][65];
    int r0 = blockIdx.x * 64, k0 = blockIdx.y * 64;
    int tid = threadIdx.x;
    int l = tid & 63, w = tid >> 6;
#pragma unroll
    for (int i = 0; i < 16; ++i) {
        int row = r0 + i * 4 + w;
        t[i * 4 + w][l] = (row < rlimit) ? src[row * 256 + k0 + l] : 0.0f;
    }
    __syncthreads();
    float nrm = (r0 + l < rlimit) ? norms[r0 + l] : 1.0f;
#pragma unroll
    for (int i = 0; i < 16; ++i) {
        int kk = i * 4 + w;
        dst[(k0 + kk) * dstride + r0 + l] = t[l][kk] / nrm;
    }
}

// ---------- sim = xn @ WnT, fused argmax. Block tile 64 tokens x 128 vocab ----------
__global__ __launch_bounds__(256) void k_sim(const float* __restrict__ xnt, const float* __restrict__ wnt,
                                             float* __restrict__ pval, int* __restrict__ pidx) {
    __shared__ float As[64][68];   // [k][token], 16B-aligned rows
    __shared__ float Bs[64][132];  // [k][vocab]
    int m0 = blockIdx.x * 64;
    int vbase = blockIdx.y * VPER;
    int tid = threadIdx.x;
    int l = tid & 63, w = tid >> 6;
    int tx = tid & 15, ty = tid >> 4;

    float best[4];
    int bidx[4];
#pragma unroll
    for (int i = 0; i < 4; ++i) { best[i] = -2.0f; bidx[i] = 0; }

    for (int vt = 0; vt < VPER / 128; ++vt) {
        float acc[4][8];
#pragma unroll
        for (int i = 0; i < 4; ++i)
#pragma unroll
            for (int j = 0; j < 8; ++j) acc[i][j] = 0.0f;

        for (int kc = 0; kc < 4; ++kc) {
#pragma unroll
            for (int i = 0; i < 16; ++i) {
                int kk = i * 4 + w;
                As[kk][l] = xnt[(kc * 64 + kk) * NTOKP + m0 + l];
            }
#pragma unroll
            for (int i = 0; i < 16; ++i) {
                int kk = i * 4 + w;
                const float* brow = &wnt[(kc * 64 + kk) * VOCAB + vbase + vt * 128];
                Bs[kk][l] = brow[l];
                Bs[kk][64 + l] = brow[64 + l];
            }
            __syncthreads();
#pragma unroll 4
            for (int kk = 0; kk < 64; ++kk) {
                float4 a = *(const float4*)&As[kk][ty * 4];
                float4 b0 = *(const float4*)&Bs[kk][tx * 4];
                float4 b1 = *(const float4*)&Bs[kk][64 + tx * 4];
                float av[4] = {a.x, a.y, a.z, a.w};
                float bv[8] = {b0.x, b0.y, b0.z, b0.w, b1.x, b1.y, b1.z, b1.w};
#pragma unroll
                for (int i = 0; i < 4; ++i)
#pragma unroll
                    for (int j = 0; j < 8; ++j) acc[i][j] += av[i] * bv[j];
            }
            __syncthreads();
        }
        // argmax update: columns visited in ascending index order per thread -> strict > keeps first max
#pragma unroll
        for (int i = 0; i < 4; ++i)
#pragma unroll
            for (int j = 0; j < 8; ++j) {
                int col = (j < 4) ? (tx * 4 + j) : (64 + tx * 4 + (j - 4));
                float v = acc[i][j];
                int c = vbase + vt * 128 + col;
                if (v > best[i] || (v == best[i] && c < bidx[i])) { best[i] = v; bidx[i] = c; }
            }
    }

    // block-level reduce: 16 candidates per token -> 1
    __syncthreads();
    float* sv = &As[0][0];   // reuse (4352 floats >= 1024)
    int* si = (int*)&Bs[0][0];
#pragma unroll
    for (int i = 0; i < 4; ++i) {
        sv[(ty * 4 + i) * 16 + tx] = best[i];
        si[(ty * 4 + i) * 16 + tx] = bidx[i];
    }
    __syncthreads();
    if (tid < 64) {
        float bv = -2.0f;
        int bi = 0x7FFFFFFF;
#pragma unroll
        for (int x = 0; x < 16; ++x) {
            float v = sv[tid * 16 + x];
            int id = si[tid * 16 + x];
            if (v > bv || (v == bv && id < bi)) { bv = v; bi = id; }
        }
        pval[blockIdx.y * NTOKP + m0 + tid] = bv;
        pidx[blockIdx.y * NTOKP + m0 + tid] = bi;
    }
}

// ---------- epilogue: reduce splits, gather W[idx], write fhat, loss partials, used mask ----------
__global__ __launch_bounds__(256) void k_gather(const float* __restrict__ pval, const int* __restrict__ pidx,
                                                const float* __restrict__ W, const float* __restrict__ tok,
                                                float* __restrict__ out, float* __restrict__ acc,
                                                unsigned int* __restrict__ used) {
    int t = blockIdx.x * 4 + (threadIdx.x >> 6);
    int lane = threadIdx.x & 63;
    float bv = -2.0f;
    int bi = 0x7FFFFFFF;
#pragma unroll
    for (int s = 0; s < VSPLIT; ++s) {
        float v = pval[s * NTOKP + t];
        int id = pidx[s * NTOKP + t];
        if (v > bv || (v == bv && id < bi)) { bv = v; bi = id; }
    }
    float4 wv = *(const float4*)&W[bi * 256 + lane * 4];
    float4 xv = *(const float4*)&tok[t * 256 + lane * 4];
    float dx = wv.x - xv.x, dy = wv.y - xv.y, dz = wv.z - xv.z, dw = wv.w - xv.w;
    float s = dx * dx + dy * dy + dz * dz + dw * dw;
#pragma unroll
    for (int off = 32; off > 0; off >>= 1) s += __shfl_down(s, off);
    if (lane == 0) {
        atomicAdd(acc, s);
        atomicOr(&used[bi >> 5], 1u << (bi & 31));
    }
    int b = t / 257, r = t % 257;
    if (r == 0) {
        *(float4*)&out[b * 256 + lane * 4] = wv;   // fhat_class (B,1,C)
    } else {
        int p = r - 1;
        float* o1 = out + 8192 + b * 65536 + p;    // fhat_patch (B,C,H,W)
        int c = lane * 4;
        o1[(c + 0) * 256] = wv.x;
        o1[(c + 1) * 256] = wv.y;
        o1[(c + 2) * 256] = wv.z;
        o1[(c + 3) * 256] = wv.w;
    }
}

__global__ __launch_bounds__(256) void k_final(const unsigned int* __restrict__ used,
                                               const float* __restrict__ acc, float* __restrict__ out) {
    int tid = threadIdx.x;
    int cnt = 0;
    for (int i = tid; i < VOCAB / 32; i += 256) cnt += __popc(used[i]);
#pragma unroll
    for (int off = 32; off > 0; off >>= 1) cnt += __shfl_down(cnt, off);
    __shared__ int p4[4];
    if ((tid & 63) == 0) p4[tid >> 6] = cnt;
    __syncthreads();
    if (tid == 0) {
        int c = p4[0] + p4[1] + p4[2] + p4[3];
        out[8192 + 2097152] = 1.25f * acc[0] / (float)(NTOK * WIDTH);       // vq_loss
        out[8192 + 2097152 + 1] = 100.0f * (float)c / (float)VOCAB;        // vocab_usage
    }
}

extern "C" void kernel_launch(void* const* d_in, const int* in_sizes, int n_in,
                              void* d_out, int out_size, void* d_ws, size_t ws_size,
                              hipStream_t stream) {
    (void)in_sizes; (void)n_in; (void)out_size; (void)ws_size;
    const float* cls = (const float*)d_in[0];
    const float* patch = (const float*)d_in[1];
    const float* W = (const float*)d_in[2];
    float* out = (float*)d_out;

    float* ws = (float*)d_ws;
    float* tok = ws;                         // NTOK*256
    float* xnt = tok + NTOK * 256;           // 256*NTOKP   (K-major normalized tokens)
    float* wnt = xnt + 256 * NTOKP;          // 256*VOCAB   (K-major normalized codebook)
    float* ntok = wnt + 256 * VOCAB;         // NTOK
    float* nw = ntok + NTOK;                 // VOCAB
    float* pval = nw + VOCAB;                // VSPLIT*NTOKP
    int* pidx = (int*)(pval + VSPLIT * NTOKP);
    float* acc = (float*)(pidx + VSPLIT * NTOKP);
    unsigned int* used = (unsigned int*)(acc + 1);  // VOCAB/32 words

    hipMemsetAsync(acc, 0, (1 + VOCAB / 32) * sizeof(float), stream);

    k_class<<<NB, 256, 0, stream>>>(cls, tok);
    k_patch<<<dim3(4, 4, NB), 256, 0, stream>>>(patch, tok);
    k_rownorm<<<NTOK / 4, 256, 0, stream>>>(tok, ntok);
    k_rownorm<<<VOCAB / 4, 256, 0, stream>>>(W, nw);
    k_transpose_scale<<<dim3(129, 4), 256, 0, stream>>>(tok, ntok, xnt, NTOKP, NTOK);
    k_transpose_scale<<<dim3(256, 4), 256, 0, stream>>>(W, nw, wnt, VOCAB, VOCAB);
    k_sim<<<dim3(129, VSPLIT), 256, 0, stream>>>(xnt, wnt, pval, pidx);
    k_gather<<<NTOK / 4, 256, 0, stream>>>(pval, pidx, W, tok, out, acc, used);
    k_final<<<1, 256, 0, stream>>>(used, acc, out);
}

// Round 2
// 506.307 us; speedup vs baseline: 2.4410x; 2.4410x over previous
//
#include <hip/hip_runtime.h>
#include <stdint.h>

#define VOCAB 16384
#define NB 32
#define NTOK 8224      // 32*257
#define MT 65          // M tiles of 128
#define MP 8320        // MT*128 padded token count
#define NT 128         // N tiles of 128
#define TILE_BYTES 131072   // per 128-row tile: 8 ksteps * 16 KB
#define STEP_BYTES 16384    // per kstep: 8 chunks * 2 (hi/lo) * 1024 B

typedef _Float16 half8 __attribute__((ext_vector_type(8)));
typedef float f4 __attribute__((ext_vector_type(4)));
typedef __attribute__((address_space(1))) const uint32_t* gas_t;
typedef __attribute__((address_space(3))) uint32_t* las_t;

__device__ __forceinline__ void async16(const void* g, void* l) {
    __builtin_amdgcn_global_load_lds((gas_t)g, (las_t)l, 16, 0, 0);
}

// ---------- build token matrix tok[NTOK][256] ----------
__global__ __launch_bounds__(256) void k_class(const float* __restrict__ cls, float* __restrict__ tok) {
    int b = blockIdx.x, c = threadIdx.x;
    tok[(b * 257) * 256 + c] = cls[b * 256 + c];
}

__global__ __launch_bounds__(256) void k_patch(const float* __restrict__ patch, float* __restrict__ tok) {
    __shared__ float t[64][65];
    int c0 = blockIdx.x * 64, p0 = blockIdx.y * 64, b = blockIdx.z;
    int tid = threadIdx.x;
    int l = tid & 63, w = tid >> 6;
    const float* src = patch + b * 65536;
#pragma unroll
    for (int i = 0; i < 16; ++i) {
        int row = i * 4 + w;
        t[row][l] = src[(c0 + row) * 256 + p0 + l];
    }
    __syncthreads();
#pragma unroll
    for (int i = 0; i < 16; ++i) {
        int prow = i * 4 + w;
        tok[(b * 257 + 1 + p0 + prow) * 256 + c0 + l] = t[l][prow];
    }
}

// ---------- row L2 norms (one wave per row) ----------
__global__ __launch_bounds__(256) void k_rownorm(const float* __restrict__ src, float* __restrict__ norms) {
    int r = blockIdx.x * 4 + (threadIdx.x >> 6);
    int lane = threadIdx.x & 63;
    float4 v = *(const float4*)&src[(size_t)r * 256 + lane * 4];
    float s = v.x * v.x + v.y * v.y + v.z * v.z + v.w * v.w;
#pragma unroll
    for (int off = 32; off > 0; off >>= 1) s += __shfl_down(s, off);
    if (lane == 0) norms[r] = fmaxf(sqrtf(s), 1e-12f);
}

// ---------- pack normalized rows into MFMA fragment-order hi/lo f16 ----------
// layout: [tile][kstep(8)][chunk16rows(8)][hi/lo(2)][ q(4) x m_local(16) x 8 f16 = 1024B ]
__global__ __launch_bounds__(256) void k_pack(const float* __restrict__ src, const float* __restrict__ norms,
                                              char* __restrict__ dst, int nrows) {
    __shared__ float t[16][264];
    __shared__ float sn[16];
    int g = blockIdx.x;              // tile*8 + chunk
    int row0 = g * 16;
    int tid = threadIdx.x;
    int rr = tid >> 4, cb = tid & 15;
    int grow = row0 + rr;
    const float* sp = src + (size_t)grow * 256 + cb * 16;
#pragma unroll
    for (int i = 0; i < 4; ++i) {
        float4 v = (grow < nrows) ? *(const float4*)(sp + i * 4) : make_float4(0.f, 0.f, 0.f, 0.f);
        *(float4*)&t[rr][cb * 16 + i * 4] = v;
    }
    if (tid < 16) sn[tid] = (row0 + tid < nrows) ? norms[row0 + tid] : 1.0f;
    __syncthreads();
    int c = tid & 63, pair = tid >> 6;
    int q = c >> 4, m = c & 15;
    float inv = 1.0f / sn[m];
#pragma unroll
    for (int it = 0; it < 4; ++it) {
        int combo = it * 4 + pair;   // 0..15
        int ks = combo >> 1, h = combo & 1;
        const float* rowp = &t[m][ks * 32 + q * 8];
        half8 o;
#pragma unroll
        for (int j = 0; j < 8; ++j) {
            float v = rowp[j] * inv;
            _Float16 hi = (_Float16)v;
            o[j] = h ? (_Float16)(v - (float)hi) : hi;
        }
        *(half8*)(dst + (size_t)(g >> 3) * TILE_BYTES + ks * STEP_BYTES + (g & 7) * 2048 + h * 1024 + c * 16) = o;
    }
}

// ---------- sim = xn @ WnT via 3-pass split-f16 MFMA, fused per-block argmax ----------
__global__ __launch_bounds__(256) void k_sim(const char* __restrict__ apk, const char* __restrict__ bpk,
                                             float* __restrict__ pval, int* __restrict__ pidx) {
    __shared__ char lds[32768];      // 16 KB A-tile + 16 KB B-tile
    int tid = threadIdx.x;
    int ln = tid & 63, wv = tid >> 6;
    int mh = wv >> 1, nh = wv & 1;
    int bx = blockIdx.x, by = blockIdx.y;
    const char* abase = apk + (size_t)bx * TILE_BYTES;
    const char* bbase = bpk + (size_t)by * TILE_BYTES;

    f4 acc[4][4];
#pragma unroll
    for (int i = 0; i < 4; ++i)
#pragma unroll
        for (int j = 0; j < 4; ++j) acc[i][j] = (f4){0.f, 0.f, 0.f, 0.f};

    // stage kstep 0
#pragma unroll
    for (int i = 0; i < 8; ++i) {
        int c = wv * 8 + i;
        const char* g = (c < 16 ? abase + (c << 10) : bbase + ((c - 16) << 10)) + (ln << 4);
        async16(g, lds + (c << 10));
    }

    for (int ks = 0; ks < 8; ++ks) {
        __syncthreads();             // staged tile visible (barrier drains vmcnt)
        const half8* Af = (const half8*)lds;
        const half8* Bf = (const half8*)(lds + 16384);
        half8 ah[4], al[4], bh[4], bl[4];
#pragma unroll
        for (int mi = 0; mi < 4; ++mi) {
            int c8 = (mh * 4 + mi) * 2;
            ah[mi] = Af[c8 * 64 + ln];
            al[mi] = Af[(c8 + 1) * 64 + ln];
        }
#pragma unroll
        for (int ni = 0; ni < 4; ++ni) {
            int c8 = (nh * 4 + ni) * 2;
            bh[ni] = Bf[c8 * 64 + ln];
            bl[ni] = Bf[(c8 + 1) * 64 + ln];
        }
        __syncthreads();             // all frag reads done; safe to overwrite LDS
        if (ks < 7) {
            const char* a2 = abase + (ks + 1) * STEP_BYTES;
            const char* b2 = bbase + (ks + 1) * STEP_BYTES;
#pragma unroll
            for (int i = 0; i < 8; ++i) {
                int c = wv * 8 + i;
                const char* g = (c < 16 ? a2 + (c << 10) : b2 + ((c - 16) << 10)) + (ln << 4);
                async16(g, lds + (c << 10));
            }
        }
#pragma unroll
        for (int mi = 0; mi < 4; ++mi)
#pragma unroll
            for (int ni = 0; ni < 4; ++ni) {
                acc[mi][ni] = __builtin_amdgcn_mfma_f32_16x16x32_f16(ah[mi], bh[ni], acc[mi][ni], 0, 0, 0);
                acc[mi][ni] = __builtin_amdgcn_mfma_f32_16x16x32_f16(ah[mi], bl[ni], acc[mi][ni], 0, 0, 0);
                acc[mi][ni] = __builtin_amdgcn_mfma_f32_16x16x32_f16(al[mi], bh[ni], acc[mi][ni], 0, 0, 0);
            }
    }

    // fused argmax epilogue.  C/D layout: col = ln&15 (n side), row = (ln>>4)*4 + reg (m side)
    int col = ln & 15, quad = ln >> 4;
    float* sval = (float*)lds;
    int* sidx = (int*)(lds + 2048);
#pragma unroll
    for (int mi = 0; mi < 4; ++mi)
#pragma unroll
        for (int r = 0; r < 4; ++r) {
            float bv = acc[mi][0][r];
            int bn = nh * 64 + col;
#pragma unroll
            for (int ni = 1; ni < 4; ++ni) {
                float v = acc[mi][ni][r];
                if (v > bv) { bv = v; bn = nh * 64 + ni * 16 + col; }   // ascending n: > keeps first max
            }
#pragma unroll
            for (int off = 1; off < 16; off <<= 1) {
                float v2 = __shfl_xor(bv, off);
                int n2 = __shfl_xor(bn, off);
                if (v2 > bv || (v2 == bv && n2 < bn)) { bv = v2; bn = n2; }
            }
            if (col == 0) {
                int ml = mh * 64 + mi * 16 + quad * 4 + r;
                sval[ml * 2 + nh] = bv;
                sidx[ml * 2 + nh] = bn;
            }
        }
    __syncthreads();
    if (tid < 128) {
        float v0 = sval[tid * 2], v1 = sval[tid * 2 + 1];
        int i0 = sidx[tid * 2], i1 = sidx[tid * 2 + 1];
        bool t1 = (v1 > v0) || (v1 == v0 && i1 < i0);
        pval[(size_t)by * MP + bx * 128 + tid] = t1 ? v1 : v0;
        pidx[(size_t)by * MP + bx * 128 + tid] = (t1 ? i1 : i0) + by * 128;
    }
}

// ---------- reduce 128 partials, gather W[idx], write fhat, loss, used mask ----------
__global__ __launch_bounds__(256) void k_gather(const float* __restrict__ pval, const int* __restrict__ pidx,
                                                const float* __restrict__ W, const float* __restrict__ tok,
                                                float* __restrict__ out, float* __restrict__ acc,
                                                unsigned int* __restrict__ used) {
    int t = blockIdx.x * 4 + (threadIdx.x >> 6);
    int ln = threadIdx.x & 63;
    float bv = -3.0f;
    int bn = 0x7FFFFFFF;
#pragma unroll
    for (int s = 0; s < 2; ++s) {
        int sp = s * 64 + ln;
        float v = pval[(size_t)sp * MP + t];
        int id = pidx[(size_t)sp * MP + t];
        if (v > bv || (v == bv && id < bn)) { bv = v; bn = id; }
    }
#pragma unroll
    for (int off = 1; off < 64; off <<= 1) {
        float v2 = __shfl_xor(bv, off);
        int n2 = __shfl_xor(bn, off);
        if (v2 > bv || (v2 == bv && n2 < bn)) { bv = v2; bn = n2; }
    }
    int bi = bn;
    float4 wv = *(const float4*)&W[(size_t)bi * 256 + ln * 4];
    float4 xv = *(const float4*)&tok[(size_t)t * 256 + ln * 4];
    float dx = wv.x - xv.x, dy = wv.y - xv.y, dz = wv.z - xv.z, dw = wv.w - xv.w;
    float s = dx * dx + dy * dy + dz * dz + dw * dw;
#pragma unroll
    for (int off = 32; off > 0; off >>= 1) s += __shfl_down(s, off);
    if (ln == 0) {
        atomicAdd(acc, s);
        atomicOr(&used[bi >> 5], 1u << (bi & 31));
    }
    int b = t / 257, r = t % 257;
    if (r == 0) {
        *(float4*)&out[b * 256 + ln * 4] = wv;       // fhat_class (B,1,C)
    } else {
        int p = r - 1;
        float* o1 = out + 8192 + b * 65536 + p;      // fhat_patch (B,C,H,W)
        int c = ln * 4;
        o1[(c + 0) * 256] = wv.x;
        o1[(c + 1) * 256] = wv.y;
        o1[(c + 2) * 256] = wv.z;
        o1[(c + 3) * 256] = wv.w;
    }
}

__global__ __launch_bounds__(256) void k_final(const unsigned int* __restrict__ used,
                                               const float* __restrict__ acc, float* __restrict__ out) {
    int tid = threadIdx.x;
    int cnt = 0;
    for (int i = tid; i < VOCAB / 32; i += 256) cnt += __popc(used[i]);
#pragma unroll
    for (int off = 32; off > 0; off >>= 1) cnt += __shfl_down(cnt, off);
    __shared__ int p4[4];
    if ((tid & 63) == 0) p4[tid >> 6] = cnt;
    __syncthreads();
    if (tid == 0) {
        int c = p4[0] + p4[1] + p4[2] + p4[3];
        out[8192 + 2097152] = 1.25f * acc[0] / (float)(NTOK * 256);    // vq_loss
        out[8192 + 2097152 + 1] = 100.0f * (float)c / (float)VOCAB;    // vocab_usage
    }
}

extern "C" void kernel_launch(void* const* d_in, const int* in_sizes, int n_in,
                              void* d_out, int out_size, void* d_ws, size_t ws_size,
                              hipStream_t stream) {
    (void)in_sizes; (void)n_in; (void)out_size; (void)ws_size;
    const float* cls = (const float*)d_in[0];
    const float* patch = (const float*)d_in[1];
    const float* W = (const float*)d_in[2];
    float* out = (float*)d_out;

    float* ws = (float*)d_ws;
    float* tok = ws;                              // 8224*256 = 2,105,344 f
    float* ntok = tok + 2105344;                  // 8320 f
    float* nw = ntok + 8320;                      // 16384 f
    char* apk = (char*)(nw + 16384);              // 65*131072  = 8,519,680 B
    char* bpk = apk + (size_t)MT * TILE_BYTES;    // 128*131072 = 16,777,216 B
    float* pval = (float*)(bpk + (size_t)NT * TILE_BYTES);  // 128*8320 f
    int* pidx = (int*)(pval + (size_t)NT * MP);             // 128*8320 i
    float* acc = (float*)(pidx + (size_t)NT * MP);
    unsigned int* used = (unsigned int*)(acc + 1);          // 512 u32

    hipMemsetAsync(acc, 0, (1 + VOCAB / 32) * sizeof(float), stream);

    k_class<<<NB, 256, 0, stream>>>(cls, tok);
    k_patch<<<dim3(4, 4, NB), 256, 0, stream>>>(patch, tok);
    k_rownorm<<<NTOK / 4, 256, 0, stream>>>(tok, ntok);
    k_rownorm<<<VOCAB / 4, 256, 0, stream>>>(W, nw);
    k_pack<<<MT * 8, 256, 0, stream>>>(tok, ntok, apk, NTOK);
    k_pack<<<NT * 8, 256, 0, stream>>>(W, nw, bpk, VOCAB);
    k_sim<<<dim3(MT, NT), 256, 0, stream>>>(apk, bpk, pval, pidx);
    k_gather<<<NTOK / 4, 256, 0, stream>>>(pval, pidx, W, tok, out, acc, used);
    k_final<<<1, 256, 0, stream>>>(used, acc, out);
}